// Round 13
// baseline (102.933 us; speedup 1.0000x reference)
//
#include <hip/hip_runtime.h>
#include <math.h>

#define SEQ   3000
#define FDIM  64
// 999 steps = 111 groups (g0..g110) x 9 steps. Channel-parallel quads (R9):
// lane p computes channel p; lane3 mirrors ch2. R13: each lane advances TWO
// independent chains (adjacent f = 2j, 2j+1), instruction-zipped inside the
// asm blocks (A,B,A,B,...) so chain A's dependency stalls are filled by
// chain B's instructions. 256 blocks x 64 threads = 256 waves x 32 chains.
// R12 vmem skeleton: quad-buffered asm loads, counted s_waitcnt vmcnt(N)
// (never 0 in loop); per group 18 ld + 18 st -> boundary vmcnt(54).

#define PPWc  0.23164189f                  // 0.3275911 / sqrt(2)
#define B1f   0.127414796f                 // 0.5*0.254829592
#define B2f   (-0.142248368f)              // 0.5*-0.284496736
#define B3f   0.7107068705f                // 0.5*1.421413741
#define B4f   (-0.7265760135f)             // 0.5*-1.453152027
#define B5f   0.5307027145f                // 0.5*1.061405429
#define NL2Ef (-0.72134752044448170368f)   // -0.5*log2(e)

#define DECL9(p) float p##0,p##1,p##2,p##3,p##4,p##5,p##6,p##7,p##8
#define TOUCH9(P) "+v"(P##0),"+v"(P##1),"+v"(P##2),"+v"(P##3),"+v"(P##4),     \
    "+v"(P##5),"+v"(P##6),"+v"(P##7),"+v"(P##8)

// two loads (chain X, chain Y) from the same 128B line
#define PF2S(dX, dY, OFF) asm volatile(                                       \
    "global_load_dword %0, %2, %4 offset:" #OFF "\n\t"                        \
    "global_load_dword %1, %3, %4 offset:" #OFF                               \
    : "=v"(dX), "=v"(dY) : "v"(voffX), "v"(voffY), "s"(lbase) : "memory")

// two stores from the fresh states (VMEM stores latch data at issue)
#define ST2(OFF) asm volatile(                                                \
    "global_store_dword %0, %2, %4 offset:" #OFF "\n\t"                       \
    "global_store_dword %1, %3, %4 offset:" #OFF                              \
    :: "v"(voffX), "v"(voffY), "v"(sx), "v"(sy), "s"(obase) : "memory")

#define WAITVM2(Nlit, PX, PY) do {                                            \
    asm volatile("s_waitcnt vmcnt(" #Nlit ")"                                 \
                 : TOUCH9(PX), TOUCH9(PY) : : "memory");                      \
    __builtin_amdgcn_sched_barrier(0);                                        \
} while (0)

// --- zipped chain head: matvec + trans launches for BOTH chains ---
#define ASMA2() asm volatile(                                                 \
    "v_fma_f32 %[aX], %[wa], %[sX], %[q]\n\t"                                 \
    "v_fma_f32 %[aY], %[wa], %[sY], %[q]\n\t"                                 \
    "v_mov_b32_dpp %[d1X], %[sX] quad_perm:[1,2,0,0] row_mask:0xf bank_mask:0xf\n\t" \
    "v_mov_b32_dpp %[d1Y], %[sY] quad_perm:[1,2,0,0] row_mask:0xf bank_mask:0xf\n\t" \
    "v_mov_b32_dpp %[d2X], %[sX] quad_perm:[2,0,1,1] row_mask:0xf bank_mask:0xf\n\t" \
    "v_mov_b32_dpp %[d2Y], %[sY] quad_perm:[2,0,1,1] row_mask:0xf bank_mask:0xf\n\t" \
    "v_fmac_f32 %[aX], %[wb], %[d1X]\n\t"                                     \
    "v_fmac_f32 %[aY], %[wb], %[d1Y]\n\t"                                     \
    "v_fmac_f32 %[aX], %[wc], %[d2X]\n\t"                                     \
    "v_fmac_f32 %[aY], %[wc], %[d2Y]\n\t"                                     \
    "v_mul_f32 %[u2X], %[aX], %[aX]\n\t"                                      \
    "v_mul_f32 %[u2Y], %[aY], %[aY]\n\t"                                      \
    "v_max_f32 %[rlX], 0, %[aX]\n\t"                                          \
    "v_max_f32 %[rlY], 0, %[aY]\n\t"                                          \
    "v_fma_f32 %[ddX], %[ppw], abs(%[aX]), 1.0\n\t"                           \
    "v_fma_f32 %[ddY], %[ppw], abs(%[aY]), 1.0\n\t"                           \
    "v_mul_f32 %[u2X], %[u2X], %[nl2e]\n\t"                                   \
    "v_mul_f32 %[u2Y], %[u2Y], %[nl2e]\n\t"                                   \
    "v_rcp_f32 %[rX], %[ddX]\n\t"                                             \
    "v_rcp_f32 %[rY], %[ddY]\n\t"                                             \
    "v_exp_f32 %[eX], %[u2X]\n\t"                                             \
    "v_exp_f32 %[eY], %[u2Y]"                                                 \
    : [aX]"=&v"(aX_), [d1X]"=&v"(d1X_), [d2X]"=&v"(d2X_), [u2X]"=&v"(u2X_),   \
      [ddX]"=&v"(ddX_), [rX]"=&v"(rX_), [eX]"=&v"(eX_), [rlX]"=&v"(rlX_),     \
      [aY]"=&v"(aY_), [d1Y]"=&v"(d1Y_), [d2Y]"=&v"(d2Y_), [u2Y]"=&v"(u2Y_),   \
      [ddY]"=&v"(ddY_), [rY]"=&v"(rY_), [eY]"=&v"(eY_), [rlY]"=&v"(rlY_)      \
    : [sX]"v"(sx), [sY]"v"(sy), [wa]"v"(wA), [wb]"v"(wB), [wc]"v"(wC),        \
      [q]"v"(q), [ppw]"v"(cPPW), [nl2e]"v"(cNL2E))

// --- zipped 9-hop tail: c23 doubles as pp; z doubles as zr ---
#define ASMB2(UX, UY) asm volatile(                                           \
    "v_fma_f32 %[c01X], %[b2], %[rX], %[b1]\n\t"                              \
    "v_fma_f32 %[c01Y], %[b2], %[rY], %[b1]\n\t"                              \
    "v_fma_f32 %[c23X], %[b4], %[rX], %[b3]\n\t"                              \
    "v_fma_f32 %[c23Y], %[b4], %[rY], %[b3]\n\t"                              \
    "v_mul_f32 %[rrX], %[rX], %[rX]\n\t"                                      \
    "v_mul_f32 %[rrY], %[rY], %[rY]\n\t"                                      \
    "v_mul_f32 %[zX], -abs(%[aX]), %[eX]\n\t"                                 \
    "v_mul_f32 %[zY], -abs(%[aY]), %[eY]\n\t"                                 \
    "v_add_f32 %[rluX], %[rlX], %[uX]\n\t"                                    \
    "v_add_f32 %[rluY], %[rlY], %[uY]\n\t"                                    \
    "v_fma_f32 %[c23X], %[c23X], %[rrX], %[c01X]\n\t"                         \
    "v_fma_f32 %[c23Y], %[c23Y], %[rrY], %[c01Y]\n\t"                         \
    "v_mul_f32 %[r4X], %[rrX], %[rrX]\n\t"                                    \
    "v_mul_f32 %[r4Y], %[rrY], %[rrY]\n\t"                                    \
    "v_mul_f32 %[zX], %[zX], %[rX]\n\t"                                       \
    "v_mul_f32 %[zY], %[zY], %[rY]\n\t"                                       \
    "v_fmac_f32 %[c23X], %[b5], %[r4X]\n\t"                                   \
    "v_fmac_f32 %[c23Y], %[b5], %[r4Y]\n\t"                                   \
    "v_fma_f32 %[sX], %[c23X], %[zX], %[rluX]\n\t"                            \
    "v_fma_f32 %[sY], %[c23Y], %[zY], %[rluY]"                                \
    : [sX]"=&v"(sx), [c01X]"=&v"(c01X_), [c23X]"=&v"(c23X_),                  \
      [rrX]"=&v"(rrX_), [r4X]"=&v"(r4X_), [zX]"=&v"(zX_), [rluX]"=&v"(rluX_), \
      [sY]"=&v"(sy), [c01Y]"=&v"(c01Y_), [c23Y]"=&v"(c23Y_),                  \
      [rrY]"=&v"(rrY_), [r4Y]"=&v"(r4Y_), [zY]"=&v"(zY_), [rluY]"=&v"(rluY_)  \
    : [aX]"v"(aX_), [rX]"v"(rX_), [eX]"v"(eX_), [rlX]"v"(rlX_), [uX]"v"(UX),  \
      [aY]"v"(aY_), [rY]"v"(rY_), [eY]"v"(eY_), [rlY]"v"(rlY_), [uY]"v"(UY),  \
      [b1]"v"(cB1), [b2]"v"(cB2), [b3]"v"(cB3), [b4]"v"(cB4), [b5]"v"(cB5))

// one step-pair: launch both chains, prefetch (in the trans shadow), tail, store
#define STEPP_LD(UX, UY, LX, LY, OFF) do {                                    \
    ASMA2(); PF2S(LX, LY, OFF); ASMB2(UX, UY); ST2(OFF); } while (0)
#define STEPP_NOLD(UX, UY, OFF) do {                                          \
    ASMA2(); ASMB2(UX, UY); ST2(OFF); } while (0)

// one group = 9 step-pairs; bases bump 2304 B (576 floats) every 3 steps so
// all offset immediates stay in {0,768,1536}.
#define GRP_LD(PX, PY, LX, LY) do {                                           \
    STEPP_LD(PX##0, PY##0, LX##0, LY##0, 0);                                  \
    STEPP_LD(PX##1, PY##1, LX##1, LY##1, 768);                                \
    STEPP_LD(PX##2, PY##2, LX##2, LY##2, 1536);                               \
    lbase += 576; obase += 576;                                               \
    STEPP_LD(PX##3, PY##3, LX##3, LY##3, 0);                                  \
    STEPP_LD(PX##4, PY##4, LX##4, LY##4, 768);                                \
    STEPP_LD(PX##5, PY##5, LX##5, LY##5, 1536);                               \
    lbase += 576; obase += 576;                                               \
    STEPP_LD(PX##6, PY##6, LX##6, LY##6, 0);                                  \
    STEPP_LD(PX##7, PY##7, LX##7, LY##7, 768);                                \
    STEPP_LD(PX##8, PY##8, LX##8, LY##8, 1536);                               \
    lbase += 576; obase += 576;                                               \
} while (0)

#define GRP_NOLD(PX, PY) do {                                                 \
    STEPP_NOLD(PX##0, PY##0, 0);                                              \
    STEPP_NOLD(PX##1, PY##1, 768);                                            \
    STEPP_NOLD(PX##2, PY##2, 1536);  obase += 576;                            \
    STEPP_NOLD(PX##3, PY##3, 0);                                              \
    STEPP_NOLD(PX##4, PY##4, 768);                                            \
    STEPP_NOLD(PX##5, PY##5, 1536);  obase += 576;                            \
    STEPP_NOLD(PX##6, PY##6, 0);                                              \
    STEPP_NOLD(PX##7, PY##7, 768);                                            \
    STEPP_NOLD(PX##8, PY##8, 1536);  obase += 576;                            \
} while (0)

// prologue batched loads (one group, both chains)
#define PF9B2(PX, PY) do {                                                    \
    PF2S(PX##0, PY##0, 0); PF2S(PX##1, PY##1, 768);                           \
    PF2S(PX##2, PY##2, 1536); lbase += 576;                                   \
    PF2S(PX##3, PY##3, 0); PF2S(PX##4, PY##4, 768);                           \
    PF2S(PX##5, PY##5, 1536); lbase += 576;                                   \
    PF2S(PX##6, PY##6, 0); PF2S(PX##7, PY##7, 768);                           \
    PF2S(PX##8, PY##8, 1536); lbase += 576;                                   \
} while (0)

__global__ __launch_bounds__(64, 1) void scan_kernel(
    const float* __restrict__ x,
    const float* __restrict__ w,
    const float* __restrict__ bias,
    float* __restrict__ out)
{
    const int lane = threadIdx.x;
    const int g  = lane >> 2;                    // chain-pair within wave
    const int pr = lane & 3;
    const int p  = pr < 3 ? pr : 2;              // channel; lane3 mirrors ch2

    // block -> (b, half): chains X,Y are adjacent f (one 128B line per pair);
    // each block owns whole cache lines exclusively -> no swizzle needed.
    const int b = blockIdx.x >> 1;               // 0..127
    const int h = blockIdx.x & 1;
    const int j = h * 16 + g;                    // 0..31 (f pair index)

    const int p1i = (p + 1) == 3 ? 0 : p + 1;
    const int p2i = (p + 2) >= 3 ? p - 1 : p + 2;
    float wA = w[p * 3 + p];
    float wB = w[p * 3 + p1i];
    float wC = w[p * 3 + p2i];
    float q  = bias[p];

    // constants in VGPRs (VOP3 forbids literals; 0/1.0 stay inline)
    float cPPW = PPWc, cNL2E = NL2Ef;
    float cB1 = B1f, cB2 = B2f, cB3 = B3f, cB4 = B4f, cB5 = B5f;

    // per-lane constant byte offsets; bases are uniform SGPRs
    const int voffX = p * 256 + j * 8;
    const int voffY = voffX + 4;
    const float* lbase = x   + (size_t)b * (SEQ * FDIM) + 3 * FDIM;  // row 3
    float*       obase = out + (size_t)b * (SEQ * FDIM) + 3 * FDIM;  // row 3
    const float* hbase = x   + (size_t)b * (SEQ * FDIM);             // row 0
    float*       ohead = out + (size_t)b * (SEQ * FDIM);

    // head: plain loads of s0 for both chains, touch so the compiler's own
    // waitcnt lands before any asm vmem is outstanding; asm head stores.
    float sx = *(const float*)((const char*)hbase + voffX);
    float sy = *(const float*)((const char*)hbase + voffY);
    asm volatile("" : "+v"(sx), "+v"(sy), "+v"(wA), "+v"(wB), "+v"(wC),
                      "+v"(q), "+v"(cPPW), "+v"(cNL2E), "+v"(cB1), "+v"(cB2),
                      "+v"(cB3), "+v"(cB4), "+v"(cB5));
    asm volatile("global_store_dword %0, %2, %4\n\t"
                 "global_store_dword %1, %3, %4"
                 :: "v"(voffX), "v"(voffY), "v"(sx), "v"(sy), "s"(ohead)
                 : "memory");

    float aX_, d1X_, d2X_, u2X_, ddX_, rX_, eX_, rlX_;
    float aY_, d1Y_, d2Y_, u2Y_, ddY_, rY_, eY_, rlY_;
    float c01X_, c23X_, rrX_, r4X_, zX_, rluX_;
    float c01Y_, c23Y_, rrY_, r4Y_, zY_, rluY_;

    DECL9(LAX); DECL9(LAY); DECL9(LBX); DECL9(LBY);
    DECL9(LCX); DECL9(LCY); DECL9(LDX); DECL9(LDY);

    PF9B2(LAX, LAY);                             // g0 (18 loads)
    PF9B2(LBX, LBY);                             // g1
    PF9B2(LCX, LCY);                             // g2
    // outstanding: hst(2)+54 = 56 (<=63). vmcnt(36) retires hst + LA.
    WAITVM2(36, LAX, LAY);

    // 27 iters x 4 groups: g0..g107. During group g, loads go to the buffer
    // consumed 3 groups earlier (dead). Boundary vmcnt(54): newest 54 =
    // current group's 36 + half of the prior group's -> the next-consumed
    // buffer (loaded 2 full groups = 72 vmem ops ago) is retired.
    #pragma unroll 1
    for (int t = 0; t < 27; ++t) {
        GRP_LD(LAX, LAY, LDX, LDY);   WAITVM2(54, LBX, LBY);   // g=4t
        GRP_LD(LBX, LBY, LAX, LAY);   WAITVM2(54, LCX, LCY);   // g=4t+1
        GRP_LD(LCX, LCY, LBX, LBY);   WAITVM2(54, LDX, LDY);   // g=4t+2
        GRP_LD(LDX, LDY, LCX, LCY);   WAITVM2(54, LAX, LAY);   // g=4t+3
    }

    // epilogue: g108 (LA), g109 (LB), g110 (LC); only stores remain
    GRP_NOLD(LAX, LAY);   WAITVM2(18, LBX, LBY); // newest 18 = st(g108)
    GRP_NOLD(LBX, LBY);   WAITVM2(18, LCX, LCY); // newest 18 = st(g109)
    GRP_NOLD(LCX, LCY);                          // g110
}

extern "C" void kernel_launch(void* const* d_in, const int* in_sizes, int n_in,
                              void* d_out, int out_size, void* d_ws, size_t ws_size,
                              hipStream_t stream) {
    const float* x    = (const float*)d_in[0];
    const float* w    = (const float*)d_in[1];
    const float* bias = (const float*)d_in[2];
    float* out        = (float*)d_out;

    hipLaunchKernelGGL(scan_kernel, dim3(256), dim3(64), 0, stream,
                       x, w, bias, out);
}